// Round 10
// baseline (531.036 us; speedup 1.0000x reference)
//
#include <hip/hip_runtime.h>
#include <hip/hip_bf16.h>

typedef __attribute__((ext_vector_type(8))) short bf16x8;
typedef __attribute__((ext_vector_type(4))) short short4v;
typedef __attribute__((ext_vector_type(4))) float f32x4;

#define BATCH 2
#define CH 64
#define NPIX 65536
#define HDIM 256
#define NLAYER 4
#define NBLK 512      // 128-px tiles per batch
#define PREC 4224     // k_layer partial: 4096 KF + 64 fs + 64 kgs (bf16)
#define PREC0 4160    // conv_in partial: 4096 S0 + 64 s0 (f32)

// ---- workspace byte offsets ----
#define OFS_FEAT0   0ull          // bf16 [b][px][c] : 16,777,216
#define OFS_PART    16777216ull   // S0part f32 (17,039,360) ALIASED with KFpart bf16 (8,650,752)
#define OFS_KFRED   33816576ull   // 16384 (bf16 [b][c][e])
#define OFS_S0B     33832960ull   // 16384 (bf16, symmetric)
#define OFS_S0V     33849344ull   // 512 f32
#define OFS_FS      33849856ull   // 512 f32
#define OFS_KGS     33850368ull   // 512 f32
#define OFS_E       33850880ull   // 32768 f32 (C - I)
#define OFS_DVEC    33883648ull   // 512 f32
#define OFS_CXT     33884160ull   // 16384 bf16 [b][e][c]  (CxT)
#define OFS_DX      33900544ull   // 512 f32
#define OFS_WKEFF   33901056ull   // 16384 bf16
#define OFS_WIEFF   33917440ull
#define OFS_WFEFF   33933824ull
#define OFS_WVX     33950208ull
#define OFS_BKEFF   33966592ull   // 512 f32
#define OFS_BIEFF   33967104ull
#define OFS_BFEFF   33967616ull
#define OFS_BVX     33968128ull
#define OFS_WKB     33968640ull   // 32768 bf16
#define OFS_WVB     34001408ull
#define OFS_WGB     34034176ull   // 65536
#define OFS_WPB     34099712ull
#define OFS_WQTB    34132480ull   // 32768 bf16 [l][e][c]
#define OFS_WTOUTE  34165248ull   // 9216 f32 [b][o*9+k][64]
#define OFS_BTAP    34174464ull   // 160 f32 [b][18]

__device__ __forceinline__ float sigmoidf_(float x){ return 1.0f/(1.0f+__expf(-x)); }
__device__ __forceinline__ short f2bs(float x){
  unsigned u = __float_as_uint(x);
  u += 0x7fffu + ((u >> 16) & 1u);
  return (short)(u >> 16);
}
__device__ __forceinline__ float bs2f(short s){
  return __uint_as_float(((unsigned)(unsigned short)s) << 16);
}

// A-frag loader: rows (w*16+m), row stride rs (shorts)
__device__ __forceinline__ void loadAfrag(bf16x8 A[2], const short* base, int rs,
                                          int m, int quad, int w){
  #pragma unroll
  for (int kc=0;kc<2;kc++)
    A[kc] = *(const bf16x8*)&base[(w*16+m)*rs + kc*32 + quad*8];
}
// 64x64x64 GEMM quarter: out[et] = sum_kc mfma(A[kc], B(et,kc)); B rows (et*16+m), stride rs
__device__ __forceinline__ void gemm64(const bf16x8 A[2], const short* Bbase, int rs,
                                       int m, int quad, f32x4 out[4]){
  #pragma unroll
  for (int et=0; et<4; et++){
    f32x4 a = {0.f,0.f,0.f,0.f};
    #pragma unroll
    for (int kc=0; kc<2; kc++){
      bf16x8 B = *(const bf16x8*)&Bbase[(et*16+m)*rs + kc*32 + quad*8];
      a = __builtin_amdgcn_mfma_f32_16x16x32_bf16(A[kc], B, a, 0,0,0);
    }
    out[et] = a;
  }
}

// ---------- weight pre-convert ----------
__global__ void k_prepw(const float* __restrict__ Wk, const float* __restrict__ Wv,
                        const float* __restrict__ Wg, const float* __restrict__ Wp,
                        const float* __restrict__ Wq,
                        short* __restrict__ Wkb, short* __restrict__ Wvb,
                        short* __restrict__ Wgb, short* __restrict__ Wpb,
                        short* __restrict__ Wqtb){
  int i = blockIdx.x*256 + threadIdx.x;
  if (i < 16384){
    Wkb[i] = f2bs(Wk[i]);
    Wvb[i] = f2bs(Wv[i]);
    Wpb[i] = f2bs(Wp[i]);
    int l = i >> 12, within = i & 4095;
    int e = within >> 6, c = within & 63;
    Wqtb[i] = f2bs(Wq[l*4096 + c*64 + e]);
  }
  if (i < 32768) Wgb[i] = f2bs(Wg[i]);
}

// ---------- conv3x3 2->64 -> bf16 feat0 [px][c]; S0/s0 partials ----------
__global__ __launch_bounds__(256) void k_conv_in(
    const float* __restrict__ x, const float* __restrict__ w,
    const float* __restrict__ bias, short* __restrict__ feat0,
    float* __restrict__ part){
  int b = blockIdx.y, blk = blockIdx.x, t = threadIdx.x;
  int pxl = t >> 1, half = t & 1, c0 = half*32;
  int n = blk*128 + pxl;
  int y = n >> 8, xx = n & 255;
  __shared__ short s_fT[64*136];

  float patch[18];
  int idx = 0;
  #pragma unroll
  for (int ci=0; ci<2; ci++)
    #pragma unroll
    for (int dy=-1; dy<=1; dy++)
      #pragma unroll
      for (int dx=-1; dx<=1; dx++){
        int yy = y+dy, xc = xx+dx;
        float v = 0.f;
        if (yy>=0 && yy<HDIM && xc>=0 && xc<HDIM)
          v = x[((b*2+ci)*HDIM + yy)*HDIM + xc];
        patch[idx++] = v;
      }
  short* fb = feat0 + ((size_t)b*NPIX + n)*64 + c0;
  #pragma unroll
  for (int c4=0; c4<8; c4++){
    short4v sv;
    #pragma unroll
    for (int j=0;j<4;j++){
      int o = c0 + c4*4 + j;
      float acc = bias[o];
      #pragma unroll
      for (int k=0;k<18;k++) acc += w[o*18+k]*patch[k];
      short s = f2bs(acc);
      sv[j] = s;
      s_fT[o*136 + pxl] = s;
    }
    *(short4v*)(fb + c4*4) = sv;
  }
  __syncthreads();

  float* pp = part + (size_t)(b*NBLK + blk)*PREC0;
  if (t < 64){
    float s = 0.f;
    for (int px=0; px<128; px++) s += bs2f(s_fT[t*136 + px]);
    pp[4096 + t] = s;
  }
  int wv = t >> 6, lane = t & 63, m = lane & 15, quad = lane >> 4;
  f32x4 accn[4];
  f32x4 z4 = {0.f,0.f,0.f,0.f};
  #pragma unroll
  for (int dt=0;dt<4;dt++) accn[dt] = z4;
  #pragma unroll
  for (int kc4=0; kc4<4; kc4++){
    bf16x8 a = *(const bf16x8*)&s_fT[(wv*16+m)*136 + kc4*32 + quad*8];
    #pragma unroll
    for (int dt=0; dt<4; dt++){
      bf16x8 bb = *(const bf16x8*)&s_fT[(dt*16+m)*136 + kc4*32 + quad*8];
      accn[dt] = __builtin_amdgcn_mfma_f32_16x16x32_bf16(a, bb, accn[dt], 0,0,0);
    }
  }
  #pragma unroll
  for (int dt=0;dt<4;dt++)
    #pragma unroll
    for (int r=0;r<4;r++)
      pp[(wv*16 + quad*4 + r)*64 + dt*16 + m] = accn[dt][r];
}

// ---------- reduce conv_in partials (f32) -> S0b bf16 + s0 f32 ----------
__global__ __launch_bounds__(256) void k_reduce0(const float* __restrict__ part,
                                                 short* __restrict__ s0b,
                                                 float* __restrict__ s0v){
  int b = blockIdx.y;
  int ce = blockIdx.x*256 + threadIdx.x;
  if (ce >= PREC0) return;
  const float* base = part + (size_t)b*NBLK*PREC0 + ce;
  float acc[8];
  #pragma unroll
  for (int j=0;j<8;j++) acc[j]=0.f;
  #pragma unroll 1
  for (int p=0; p<NBLK; p+=8){
    #pragma unroll
    for (int j=0;j<8;j++) acc[j] += base[(size_t)(p+j)*PREC0];
  }
  float s = ((acc[0]+acc[1])+(acc[2]+acc[3])) + ((acc[4]+acc[5])+(acc[6]+acc[7]));
  if (ce < 4096) s0b[b*4096 + ce] = f2bs(s);
  else           s0v[b*64 + ce - 4096] = s;
}

// ---------- per-layer big kernel: k/i/f (folded weights on feat0) + KF; ONE barrier ----------
__global__ __launch_bounds__(256,3) void k_layer(
    const short* __restrict__ feat0,
    const short* __restrict__ wkeff, const float* __restrict__ bkeff,
    const short* __restrict__ wieff, const float* __restrict__ bieff,
    const short* __restrict__ wfeff, const float* __restrict__ bfeff,
    short* __restrict__ kfpart)
{
  int b = blockIdx.y;
  int n0 = blockIdx.x * 128;
  int t = threadIdx.x;
  int w = t >> 6, lane = t & 63, m = lane & 15, quad = lane >> 4;
  int rowbase = w*16;

  __shared__ short s_fT[64*136];
  __shared__ short s_kg[64*136];

  const short* fb = feat0 + ((size_t)b*NPIX + n0)*64;

  // stage s_fT ([c][px]) from coalesced short4 loads
  #pragma unroll
  for (int i=0;i<8;i++){
    int chunk = t + i*256;
    int px = chunk >> 4, c0 = (chunk & 15)*4;
    short4v xv = *(const short4v*)(fb + px*64 + c0);
    #pragma unroll
    for (int j=0;j<4;j++) s_fT[(c0+j)*136 + px] = xv[j];
  }

  bf16x8 Ak[2], Ai[2], Af[2];
  loadAfrag(Ak, wkeff + b*4096, 64, m, quad, w);
  loadAfrag(Ai, wieff + b*4096, 64, m, quad, w);
  loadAfrag(Af, wfeff + b*4096, 64, m, quad, w);

  float bkv[4], biv[4], bfv[4], fs[4], kgs[4];
  #pragma unroll
  for (int r=0;r<4;r++){
    int row = rowbase + quad*4 + r;
    bkv[r] = bkeff[b*64 + row];
    biv[r] = bieff[b*64 + row];
    bfv[r] = bfeff[b*64 + row];
    fs[r] = 0.f; kgs[r] = 0.f;
  }
  f32x4 z4 = {0.f,0.f,0.f,0.f};

  #pragma unroll
  for (int half=0; half<2; half++){
    bf16x8 Bf[2][4];
    #pragma unroll
    for (int kc=0;kc<2;kc++)
      #pragma unroll
      for (int q4=0;q4<4;q4++)
        Bf[kc][q4] = *(const bf16x8*)(fb + ((half*4+q4)*16 + m)*64 + kc*32 + quad*8);
    f32x4 acck[4], acci[4], accf[4];
    #pragma unroll
    for (int q4=0;q4<4;q4++){ acck[q4]=z4; acci[q4]=z4; accf[q4]=z4; }
    #pragma unroll
    for (int kc=0;kc<2;kc++)
      #pragma unroll
      for (int q4=0;q4<4;q4++){
        acck[q4] = __builtin_amdgcn_mfma_f32_16x16x32_bf16(Ak[kc], Bf[kc][q4], acck[q4], 0,0,0);
        acci[q4] = __builtin_amdgcn_mfma_f32_16x16x32_bf16(Ai[kc], Bf[kc][q4], acci[q4], 0,0,0);
        accf[q4] = __builtin_amdgcn_mfma_f32_16x16x32_bf16(Af[kc], Bf[kc][q4], accf[q4], 0,0,0);
      }
    #pragma unroll
    for (int q4=0;q4<4;q4++){
      int nt = half*4 + q4;
      #pragma unroll
      for (int r=0;r<4;r++){
        int row = rowbase + quad*4 + r;
        float kgv = (acck[q4][r] + bkv[r]) * sigmoidf_(acci[q4][r] + biv[r]);
        s_kg[row*136 + nt*16 + m] = f2bs(kgv);
        kgs[r] += kgv;
        fs[r] += sigmoidf_(accf[q4][r] + bfv[r]);
      }
    }
  }
  __syncthreads();   // s_fT staged (cross-wave); s_kg own rows only

  // KF[c][e] = sum_px kg[c,px]*f0[e,px]
  f32x4 accn[4];
  #pragma unroll
  for (int dt=0;dt<4;dt++) accn[dt] = z4;
  #pragma unroll
  for (int kc4=0; kc4<4; kc4++){
    bf16x8 a = *(const bf16x8*)&s_kg[(rowbase + m)*136 + kc4*32 + quad*8];
    #pragma unroll
    for (int dt=0; dt<4; dt++){
      bf16x8 bx = *(const bf16x8*)&s_fT[(dt*16 + m)*136 + kc4*32 + quad*8];
      accn[dt] = __builtin_amdgcn_mfma_f32_16x16x32_bf16(a, bx, accn[dt], 0,0,0);
    }
  }

  #pragma unroll
  for (int off=1; off<16; off<<=1)
    #pragma unroll
    for (int r=0;r<4;r++){
      fs[r]  += __shfl_xor(fs[r],  off, 64);
      kgs[r] += __shfl_xor(kgs[r], off, 64);
    }
  short* kp = kfpart + (size_t)(b*NBLK + blockIdx.x)*PREC;
  #pragma unroll
  for (int dt=0;dt<4;dt++)
    #pragma unroll
    for (int r=0;r<4;r++)
      kp[(rowbase + quad*4 + r)*64 + dt*16 + m] = f2bs(accn[dt][r]);
  if (m == 0){
    #pragma unroll
    for (int r=0;r<4;r++){
      int row = rowbase + quad*4 + r;
      kp[4096 + row] = f2bs(fs[r]);
      kp[4160 + row] = f2bs(kgs[r]);
    }
  }
}

// ---------- reduce k_layer partials (bf16) ----------
__global__ __launch_bounds__(256) void k_reduce(const short* __restrict__ kfpart,
                                                short* __restrict__ kfred,
                                                float* __restrict__ fsK,
                                                float* __restrict__ kgsK){
  int b = blockIdx.y;
  int ce = blockIdx.x*256 + threadIdx.x;
  if (ce >= PREC) return;
  const short* base = kfpart + (size_t)b*NBLK*PREC + ce;
  float acc[8];
  #pragma unroll
  for (int j=0;j<8;j++) acc[j]=0.f;
  #pragma unroll 1
  for (int p=0; p<NBLK; p+=8){
    #pragma unroll
    for (int j=0;j<8;j++) acc[j] += bs2f(base[(size_t)(p+j)*PREC]);
  }
  float s = ((acc[0]+acc[1])+(acc[2]+acc[3])) + ((acc[4]+acc[5])+(acc[6]+acc[7]));
  if (ce < 4096)      kfred[b*4096 + ce] = f2bs(s);
  else if (ce < 4160) fsK[b*64 + ce - 4096] = s;
  else                kgsK[b*64 + ce - 4160] = s;
}

// ---------- compose: mem update + affine-state composition + next-layer folding ----------
__global__ __launch_bounds__(256) void k_compose(
    int phase,
    float* __restrict__ E, float* __restrict__ dvec,
    short* __restrict__ cxt, float* __restrict__ dx,
    short* __restrict__ wkeff, short* __restrict__ wieff,
    short* __restrict__ wfeff, short* __restrict__ wvx,
    float* __restrict__ bkeff, float* __restrict__ bieff,
    float* __restrict__ bfeff, float* __restrict__ bvx,
    const short* __restrict__ kfred, const float* __restrict__ fsK,
    const float* __restrict__ kgsK,
    const float* __restrict__ hidden_in, float* __restrict__ hidden_out,
    const short* __restrict__ S0b, const float* __restrict__ s0v,
    const float* __restrict__ gammaP, const float* __restrict__ betaP,
    const short* __restrict__ Wkb, const short* __restrict__ Wvb,
    const short* __restrict__ Wgb, const short* __restrict__ Wpb,
    const short* __restrict__ Wqtb, const float* __restrict__ WqF,
    const float* __restrict__ bqP, const float* __restrict__ bkP,
    const float* __restrict__ bvP, const float* __restrict__ bgP,
    const float* __restrict__ bpP,
    const float* __restrict__ WoutF, float* __restrict__ wtoutE,
    float* __restrict__ btap)
{
  int b = blockIdx.x, t = threadIdx.x;
  int w = t >> 6, lane = t & 63, m = lane & 15, quad = lane >> 4;
  __shared__ short sh1[64*72];
  __shared__ short sh2[64*72];
  __shared__ float sT[64*68];
  __shared__ float sF[64*68];
  __shared__ float sv_fm[64], sv_kgs[64], sv_u[64], sv_g[64];
  __shared__ float sv_A[64], sv_B[64], sv_dx[64], sv_sum[64], sv_sq[64], sv_gr[16];
  f32x4 z4 = {0.f,0.f,0.f,0.f};
  const float invN = 1.0f/65536.0f;

  if (phase == 0){
    #pragma unroll
    for (int i=0;i<16;i++){
      E[b*4096 + t + i*256] = 0.f;
      int idx = t + i*256;
      sF[(idx>>6)*68 + (idx&63)] = 0.f;
    }
    if (t < 64){ dvec[b*64+t] = 0.f; sv_g[t] = 0.f; }
    __syncthreads();
  } else {
    int lay = phase - 1;
    if (t < 64){
      sv_fm[t]  = fsK[b*64+t]*invN;
      sv_kgs[t] = kgsK[b*64+t]*invN;
      float u = bqP[lay*64+t];
      const float* wqrow = WqF + lay*4096 + t*64;
      for (int e=0;e<64;e++) u += wqrow[e]*dx[b*64+e];
      sv_u[t] = u;
    }
    __syncthreads();
    // mem[c][d] = fm*prev + (KF·Wvx^T)/N + kgs*bvx
    {
      bf16x8 A[2];
      loadAfrag(A, kfred + b*4096, 64, m, quad, w);
      f32x4 o4[4];
      gemm64(A, wvx + b*4096, 64, m, quad, o4);
      #pragma unroll
      for (int dt=0;dt<4;dt++)
        #pragma unroll
        for (int r=0;r<4;r++){
          int c = w*16 + quad*4 + r, d = dt*16 + m;
          float pm = hidden_in[(size_t)(b*NLAYER+lay)*4096 + c*64 + d];
          float nm = sv_fm[c]*pm + o4[dt][r]*invN + sv_kgs[c]*bvx[b*64+d];
          hidden_out[(size_t)(b*NLAYER+lay)*4096 + c*64 + d] = nm;
          sh1[c*72 + d] = f2bs(nm);
        }
    }
    __syncthreads();
    // mf[o][c] = Wp·mem^T
    {
      bf16x8 A[2];
      loadAfrag(A, Wpb + lay*4096, 64, m, quad, w);
      f32x4 o4[4];
      gemm64(A, sh1, 72, m, quad, o4);
      #pragma unroll
      for (int ct=0;ct<4;ct++)
        #pragma unroll
        for (int r=0;r<4;r++)
          sh2[(w*16 + quad*4 + r)*72 + ct*16 + m] = f2bs(o4[ct][r]);
    }
    __syncthreads();
    // g = bp + 0.125*mf·u ; P = mf·Wq
    if (t < 64){
      float acc = 0.f;
      for (int c=0;c<64;c++) acc += bs2f(sh2[t*72+c])*sv_u[c];
      sv_g[t] = bpP[lay*64+t] + 0.125f*acc;
    }
    {
      bf16x8 A[2];
      loadAfrag(A, sh2, 72, m, quad, w);
      f32x4 o4[4];
      gemm64(A, Wqtb + lay*4096, 64, m, quad, o4);
      #pragma unroll
      for (int et=0;et<4;et++)
        #pragma unroll
        for (int r=0;r<4;r++)
          sh1[(w*16 + quad*4 + r)*72 + et*16 + m] = f2bs(o4[et][r]);
    }
    __syncthreads();
    // F = 0.125 * P·Cx  -> sF (LDS)
    {
      bf16x8 A[2];
      loadAfrag(A, sh1, 72, m, quad, w);
      f32x4 o4[4];
      gemm64(A, cxt + b*4096, 64, m, quad, o4);
      #pragma unroll
      for (int et=0;et<4;et++)
        #pragma unroll
        for (int r=0;r<4;r++)
          sF[(w*16 + quad*4 + r)*68 + et*16 + m] = 0.125f*o4[et][r];
    }
    __syncthreads();
  }

  if (phase < NLAYER){
    int j = phase;
    // C bf16 = I + E + F
    #pragma unroll
    for (int i=0;i<16;i++){
      int idx = t + i*256;
      int c = idx >> 6, e = idx & 63;
      float v = E[b*4096 + idx] + sF[c*68 + e] + (c==e ? 1.f : 0.f);
      sh2[c*72 + e] = f2bs(v);
    }
    __syncthreads();
    // T = C·S0
    {
      bf16x8 A[2];
      loadAfrag(A, sh2, 72, m, quad, w);
      f32x4 o4[4];
      gemm64(A, S0b + b*4096, 64, m, quad, o4);
      #pragma unroll
      for (int et=0;et<4;et++)
        #pragma unroll
        for (int r=0;r<4;r++)
          sT[(w*16 + quad*4 + r)*68 + et*16 + m] = o4[et][r];
    }
    __syncthreads();
    if (t < 64){
      int c = t;
      float q = 0.f, m1 = 0.f;
      const float* Erow = E + b*4096 + c*64;
      for (int e=0;e<64;e++){
        float Ce = Erow[e] + sF[c*68+e] + (e==c ? 1.f : 0.f);
        q  += sT[c*68+e]*Ce;
        m1 += Ce*s0v[b*64+e];
      }
      float dc = dvec[b*64+c] + sv_g[c];
      sv_sum[c] = m1 + 65536.f*dc;
      sv_sq[c]  = q + 2.f*dc*m1 + 65536.f*dc*dc;
    }
    __syncthreads();
    if (t < 8){
      float s=0.f, sq=0.f;
      for (int c=t*8; c<t*8+8; c++){ s += sv_sum[c]; sq += sv_sq[c]; }
      float mu = s*(1.f/(8.f*65536.f));
      float var = sq*(1.f/(8.f*65536.f)) - mu*mu;
      sv_gr[t*2] = mu;
      sv_gr[t*2+1] = rsqrtf(var + 1e-5f);
    }
    __syncthreads();
    if (t < 64){
      int g = t >> 3;
      float A = sv_gr[g*2+1]*gammaP[j*64+t];
      sv_A[t] = A;
      sv_B[t] = betaP[j*64+t] - sv_gr[g*2]*A;
      float dxv = A*(dvec[b*64+t] + sv_g[t]) + sv_B[t];
      sv_dx[t] = dxv;
      dx[b*64+t] = dxv;
    }
    __syncthreads();
    // CxT[e][c] = A_c * C[c][e]
    #pragma unroll
    for (int i=0;i<16;i++){
      int idx = t + i*256;
      int c = idx >> 6, e = idx & 63;
      float v = (E[b*4096 + idx] + sF[c*68+e] + (c==e ? 1.f : 0.f))*sv_A[c];
      cxt[b*4096 + e*64 + c] = f2bs(v);
    }
    __syncthreads();
    // folded weights: W_eff = W·Cx
    {
      bf16x8 A[2]; f32x4 o4[4];
      loadAfrag(A, Wkb + j*4096, 64, m, quad, w);
      gemm64(A, cxt + b*4096, 64, m, quad, o4);
      #pragma unroll
      for (int et=0;et<4;et++)
        #pragma unroll
        for (int r=0;r<4;r++)
          wkeff[b*4096 + (w*16+quad*4+r)*64 + et*16+m] = f2bs(o4[et][r]);
      loadAfrag(A, Wgb + j*8192 + 64*64, 64, m, quad, w);
      gemm64(A, cxt + b*4096, 64, m, quad, o4);
      #pragma unroll
      for (int et=0;et<4;et++)
        #pragma unroll
        for (int r=0;r<4;r++)
          wieff[b*4096 + (w*16+quad*4+r)*64 + et*16+m] = f2bs(o4[et][r]);
      loadAfrag(A, Wgb + j*8192, 64, m, quad, w);
      gemm64(A, cxt + b*4096, 64, m, quad, o4);
      #pragma unroll
      for (int et=0;et<4;et++)
        #pragma unroll
        for (int r=0;r<4;r++)
          wfeff[b*4096 + (w*16+quad*4+r)*64 + et*16+m] = f2bs(o4[et][r]);
      loadAfrag(A, Wvb + j*4096, 64, m, quad, w);
      gemm64(A, cxt + b*4096, 64, m, quad, o4);
      #pragma unroll
      for (int et=0;et<4;et++)
        #pragma unroll
        for (int r=0;r<4;r++)
          wvx[b*4096 + (w*16+quad*4+r)*64 + et*16+m] = f2bs(o4[et][r]);
    }
    if (t < 64){
      float aK = bkP[j*64+t], aI = bgP[j*128+64+t], aF = bgP[j*128+t], aV = bvP[j*64+t];
      const short* wk = Wkb + j*4096 + t*64;
      const short* wi = Wgb + j*8192 + (64+t)*64;
      const short* wf = Wgb + j*8192 + t*64;
      const short* wvr = Wvb + j*4096 + t*64;
      for (int e=0;e<64;e++){
        float d_ = sv_dx[e];
        aK += bs2f(wk[e])*d_;
        aI += bs2f(wi[e])*d_;
        aF += bs2f(wf[e])*d_;
        aV += bs2f(wvr[e])*d_;
      }
      bkeff[b*64+t] = aK; bieff[b*64+t] = aI;
      bfeff[b*64+t] = aF; bvx[b*64+t] = aV;
    }
    // persist state AFTER all readers of E/dvec in this phase.
    // (Last cross-thread E read is the CxT loop, which is followed by a barrier;
    //  only phases < NLAYER persist — phase NLAYER reads E/dvec concurrently in
    //  its wtoutE/btap loops and must NOT write them: that race caused R9's
    //  replay divergence.)
    #pragma unroll
    for (int i=0;i<16;i++){
      int idx = t + i*256;
      E[b*4096 + idx] += sF[(idx>>6)*68 + (idx&63)];
    }
    if (t < 64) dvec[b*64+t] += sv_g[t];
  } else {
    // phase == NLAYER: fold conv_out weights with C4 (E/dvec are read-only here)
    #pragma unroll 1
    for (int i=0;i<5;i++){
      int idxq = t + i*256;
      if (idxq < 1152){
        int o = idxq / 576, rem = idxq % 576;
        int k = rem >> 6, e = rem & 63;
        float acc = 0.f;
        for (int d=0; d<64; d++){
          float Cde = E[b*4096 + d*64 + e] + sF[d*68+e] + (d==e ? 1.f : 0.f);
          acc += WoutF[o*576 + d*9 + k]*Cde;
        }
        wtoutE[b*1152 + (o*9+k)*64 + e] = acc;
      }
    }
    if (t < 18){
      int o = t/9, k = t%9;
      float acc = 0.f;
      for (int d=0; d<64; d++)
        acc += WoutF[o*576 + d*9 + k]*(dvec[b*64+d] + sv_g[d]);
      btap[b*18 + t] = acc;
    }
  }
}

// ---------- conv3x3 64->2 on folded weights + residual ----------
__global__ __launch_bounds__(256) void k_conv_out(
    const short* __restrict__ feat0, const float* __restrict__ wtoutE,
    const float* __restrict__ btap, const float* __restrict__ bias,
    const float* __restrict__ xin, float* __restrict__ out){
  int b = blockIdx.y;
  int y = blockIdx.x;
  int xx = threadIdx.x;
  float acc0 = bias[0], acc1 = bias[1];
  #pragma unroll
  for (int dy=-1; dy<=1; dy++){
    int yy = y + dy;
    if (yy < 0 || yy >= HDIM) continue;
    #pragma unroll
    for (int dx=-1; dx<=1; dx++){
      int xc = xx + dx;
      if (xc >= 0 && xc < HDIM){
        int k = (dy+1)*3 + dx+1;
        const short* fp = feat0 + ((size_t)b*NPIX + yy*HDIM + xc)*64;
        const float* w0 = wtoutE + b*1152 + k*64;
        const float* w1 = wtoutE + b*1152 + 576 + k*64;
        acc0 += btap[b*18 + k];
        acc1 += btap[b*18 + 9 + k];
        #pragma unroll
        for (int c4=0;c4<16;c4++){
          short4v xs = *(const short4v*)(fp + c4*4);
          f32x4 wv0 = *(const f32x4*)(w0 + c4*4);
          f32x4 wv1 = *(const f32x4*)(w1 + c4*4);
          #pragma unroll
          for (int j=0;j<4;j++){
            float f = bs2f(xs[j]);
            acc0 += f*wv0[j];
            acc1 += f*wv1[j];
          }
        }
      }
    }
  }
  size_t p0 = (size_t)(b*2+0)*NPIX + y*HDIM + xx;
  size_t p1 = (size_t)(b*2+1)*NPIX + y*HDIM + xx;
  out[p0] = acc0 + xin[p0];
  out[p1] = acc1 + xin[p1];
}

extern "C" void kernel_launch(void* const* d_in, const int* in_sizes, int n_in,
                              void* d_out, int out_size, void* d_ws, size_t ws_size,
                              hipStream_t stream){
  char* ws = (char*)d_ws;
  short* feat0 = (short*)(ws + OFS_FEAT0);
  float* part  = (float*)(ws + OFS_PART);
  short* kfp   = (short*)(ws + OFS_PART);      // aliased (disjoint lifetime)
  short* kfred = (short*)(ws + OFS_KFRED);
  short* s0b   = (short*)(ws + OFS_S0B);
  float* s0v   = (float*)(ws + OFS_S0V);
  float* fsK   = (float*)(ws + OFS_FS);
  float* kgsK  = (float*)(ws + OFS_KGS);
  float* E     = (float*)(ws + OFS_E);
  float* dvec  = (float*)(ws + OFS_DVEC);
  short* cxt   = (short*)(ws + OFS_CXT);
  float* dx    = (float*)(ws + OFS_DX);
  short* wkeff = (short*)(ws + OFS_WKEFF);
  short* wieff = (short*)(ws + OFS_WIEFF);
  short* wfeff = (short*)(ws + OFS_WFEFF);
  short* wvx   = (short*)(ws + OFS_WVX);
  float* bkeff = (float*)(ws + OFS_BKEFF);
  float* bieff = (float*)(ws + OFS_BIEFF);
  float* bfeff = (float*)(ws + OFS_BFEFF);
  float* bvx   = (float*)(ws + OFS_BVX);
  short* wkb   = (short*)(ws + OFS_WKB);
  short* wvb   = (short*)(ws + OFS_WVB);
  short* wgb   = (short*)(ws + OFS_WGB);
  short* wpb   = (short*)(ws + OFS_WPB);
  short* wqtb  = (short*)(ws + OFS_WQTB);
  float* wtoutE= (float*)(ws + OFS_WTOUTE);
  float* btap  = (float*)(ws + OFS_BTAP);

  const float* x      = (const float*)d_in[0];
  const float* hidden = (const float*)d_in[1];
  const float* W_in   = (const float*)d_in[2];
  const float* b_in   = (const float*)d_in[3];
  const float* gamma  = (const float*)d_in[4];
  const float* beta   = (const float*)d_in[5];
  const float* Wq     = (const float*)d_in[6];
  const float* bq     = (const float*)d_in[7];
  const float* Wk     = (const float*)d_in[8];
  const float* bk     = (const float*)d_in[9];
  const float* Wv     = (const float*)d_in[10];
  const float* bv     = (const float*)d_in[11];
  const float* Wg     = (const float*)d_in[12];
  const float* bg     = (const float*)d_in[13];
  const float* Wp     = (const float*)d_in[14];
  const float* bp     = (const float*)d_in[15];
  const float* W_out  = (const float*)d_in[16];
  const float* b_out  = (const float*)d_in[17];

  float* out        = (float*)d_out;
  float* hidden_out = out + BATCH*2*NPIX;

  k_prepw<<<dim3(128), dim3(256), 0, stream>>>(Wk, Wv, Wg, Wp, Wq,
                                               wkb, wvb, wgb, wpb, wqtb);
  k_conv_in<<<dim3(NBLK, BATCH), dim3(256), 0, stream>>>(x, W_in, b_in, feat0, part);
  k_reduce0<<<dim3((PREC0+255)/256, BATCH), dim3(256), 0, stream>>>(part, s0b, s0v);

  #define COMPOSE_ARGS E, dvec, cxt, dx, wkeff, wieff, wfeff, wvx, \
      bkeff, bieff, bfeff, bvx, kfred, fsK, kgsK, hidden, hidden_out, \
      s0b, s0v, gamma, beta, wkb, wvb, wgb, wpb, wqtb, Wq, \
      bq, bk, bv, bg, bp, W_out, wtoutE, btap

  k_compose<<<dim3(BATCH), dim3(256), 0, stream>>>(0, COMPOSE_ARGS);
  for (int l=0; l<NLAYER; l++){
    k_layer<<<dim3(NBLK, BATCH), dim3(256), 0, stream>>>(
        feat0, wkeff, bkeff, wieff, bieff, wfeff, bfeff, kfp);
    k_reduce<<<dim3((PREC+255)/256, BATCH), dim3(256), 0, stream>>>(kfp, kfred, fsK, kgsK);
    k_compose<<<dim3(BATCH), dim3(256), 0, stream>>>(l+1, COMPOSE_ARGS);
  }
  k_conv_out<<<dim3(HDIM, BATCH), dim3(256), 0, stream>>>(feat0, wtoutE, btap, b_out, x, out);
}

// Round 11
// 493.251 us; speedup vs baseline: 1.0766x; 1.0766x over previous
//
#include <hip/hip_runtime.h>
#include <hip/hip_bf16.h>

typedef __attribute__((ext_vector_type(8))) short bf16x8;
typedef __attribute__((ext_vector_type(4))) short short4v;
typedef __attribute__((ext_vector_type(4))) float f32x4;

#define BATCH 2
#define CH 64
#define NPIX 65536
#define HDIM 256
#define NLAYER 4
#define NBLK 128      // blocks per batch; each handles 512 px (4 tiles of 128)
#define PREC 4224     // k_layer partial: 4096 KF + 64 fs + 64 kgs (bf16)
#define PREC0 4160    // conv_in partial: 4096 S0 + 64 s0 (f32)

// ---- workspace byte offsets ----
#define OFS_FEAT0   0ull          // bf16 [b][px][c] : 16,777,216
#define OFS_PART    16777216ull   // S0part f32 (4,259,840) ALIASED with KFpart bf16 (2,162,688)
#define OFS_KFRED   33816576ull   // 16384 (bf16 [b][c][e])
#define OFS_S0B     33832960ull   // 16384 (bf16, symmetric)
#define OFS_S0V     33849344ull   // 512 f32
#define OFS_FS      33849856ull   // 512 f32
#define OFS_KGS     33850368ull   // 512 f32
#define OFS_E       33850880ull   // 32768 f32 (C - I)
#define OFS_DVEC    33883648ull   // 512 f32
#define OFS_CXT     33884160ull   // 16384 bf16 [b][e][c]  (CxT)
#define OFS_DX      33900544ull   // 512 f32
#define OFS_WKEFF   33901056ull   // 16384 bf16
#define OFS_WIEFF   33917440ull
#define OFS_WFEFF   33933824ull
#define OFS_WVX     33950208ull
#define OFS_BKEFF   33966592ull   // 512 f32
#define OFS_BIEFF   33967104ull
#define OFS_BFEFF   33967616ull
#define OFS_BVX     33968128ull
#define OFS_WKB     33968640ull   // 32768 bf16
#define OFS_WVB     34001408ull
#define OFS_WGB     34034176ull   // 65536
#define OFS_WPB     34099712ull
#define OFS_WQTB    34132480ull   // 32768 bf16 [l][e][c]
#define OFS_WTOUTE  34165248ull   // 9216 f32 [b][o*9+k][64]
#define OFS_BTAP    34174464ull   // 160 f32 [b][18]

__device__ __forceinline__ float sigmoidf_(float x){ return 1.0f/(1.0f+__expf(-x)); }
__device__ __forceinline__ short f2bs(float x){
  unsigned u = __float_as_uint(x);
  u += 0x7fffu + ((u >> 16) & 1u);
  return (short)(u >> 16);
}
__device__ __forceinline__ float bs2f(short s){
  return __uint_as_float(((unsigned)(unsigned short)s) << 16);
}

// A-frag loader: rows (w*16+m), row stride rs (shorts)
__device__ __forceinline__ void loadAfrag(bf16x8 A[2], const short* base, int rs,
                                          int m, int quad, int w){
  #pragma unroll
  for (int kc=0;kc<2;kc++)
    A[kc] = *(const bf16x8*)&base[(w*16+m)*rs + kc*32 + quad*8];
}
// 64x64x64 GEMM quarter
__device__ __forceinline__ void gemm64(const bf16x8 A[2], const short* Bbase, int rs,
                                       int m, int quad, f32x4 out[4]){
  #pragma unroll
  for (int et=0; et<4; et++){
    f32x4 a = {0.f,0.f,0.f,0.f};
    #pragma unroll
    for (int kc=0; kc<2; kc++){
      bf16x8 B = *(const bf16x8*)&Bbase[(et*16+m)*rs + kc*32 + quad*8];
      a = __builtin_amdgcn_mfma_f32_16x16x32_bf16(A[kc], B, a, 0,0,0);
    }
    out[et] = a;
  }
}

// ---------- weight pre-convert ----------
__global__ void k_prepw(const float* __restrict__ Wk, const float* __restrict__ Wv,
                        const float* __restrict__ Wg, const float* __restrict__ Wp,
                        const float* __restrict__ Wq,
                        short* __restrict__ Wkb, short* __restrict__ Wvb,
                        short* __restrict__ Wgb, short* __restrict__ Wpb,
                        short* __restrict__ Wqtb){
  int i = blockIdx.x*256 + threadIdx.x;
  if (i < 16384){
    Wkb[i] = f2bs(Wk[i]);
    Wvb[i] = f2bs(Wv[i]);
    Wpb[i] = f2bs(Wp[i]);
    int l = i >> 12, within = i & 4095;
    int e = within >> 6, c = within & 63;
    Wqtb[i] = f2bs(Wq[l*4096 + c*64 + e]);
  }
  if (i < 32768) Wgb[i] = f2bs(Wg[i]);
}

// ---------- conv3x3 2->64 -> bf16 feat0 [px][c]; S0/s0 accumulated over 4 tiles ----------
__global__ __launch_bounds__(256) void k_conv_in(
    const float* __restrict__ x, const float* __restrict__ w,
    const float* __restrict__ bias, short* __restrict__ feat0,
    float* __restrict__ part){
  int b = blockIdx.y, blk = blockIdx.x, t = threadIdx.x;
  int pxl = t >> 1, half = t & 1, c0 = half*32;
  int wv = t >> 6, lane = t & 63, m = lane & 15, quad = lane >> 4;
  __shared__ short s_fT[64*136];

  f32x4 accn[4];
  f32x4 z4 = {0.f,0.f,0.f,0.f};
  #pragma unroll
  for (int dt=0;dt<4;dt++) accn[dt] = z4;
  float s0acc = 0.f;

  for (int tile=0; tile<4; tile++){
    if (tile) __syncthreads();   // previous tile's s_fT readers done
    int n = blk*512 + tile*128 + pxl;
    int y = n >> 8, xx = n & 255;
    float patch[18];
    int idx = 0;
    #pragma unroll
    for (int ci=0; ci<2; ci++)
      #pragma unroll
      for (int dy=-1; dy<=1; dy++)
        #pragma unroll
        for (int dx=-1; dx<=1; dx++){
          int yy = y+dy, xc = xx+dx;
          float v = 0.f;
          if (yy>=0 && yy<HDIM && xc>=0 && xc<HDIM)
            v = x[((b*2+ci)*HDIM + yy)*HDIM + xc];
          patch[idx++] = v;
        }
    short* fb = feat0 + ((size_t)b*NPIX + n)*64 + c0;
    #pragma unroll
    for (int c4=0; c4<8; c4++){
      short4v sv;
      #pragma unroll
      for (int j=0;j<4;j++){
        int o = c0 + c4*4 + j;
        float acc = bias[o];
        #pragma unroll
        for (int k=0;k<18;k++) acc += w[o*18+k]*patch[k];
        short s = f2bs(acc);
        sv[j] = s;
        s_fT[o*136 + pxl] = s;
      }
      *(short4v*)(fb + c4*4) = sv;
    }
    __syncthreads();   // s_fT staged

    // s0 row sums (vectorized LDS reads)
    if (t < 64){
      const short* row = &s_fT[t*136];
      #pragma unroll
      for (int px=0; px<128; px+=8){
        bf16x8 v = *(const bf16x8*)&row[px];
        #pragma unroll
        for (int j=0;j<8;j++) s0acc += bs2f(v[j]);
      }
    }
    // S0 MFMA accumulate
    #pragma unroll
    for (int kc4=0; kc4<4; kc4++){
      bf16x8 a = *(const bf16x8*)&s_fT[(wv*16+m)*136 + kc4*32 + quad*8];
      #pragma unroll
      for (int dt=0; dt<4; dt++){
        bf16x8 bb = *(const bf16x8*)&s_fT[(dt*16+m)*136 + kc4*32 + quad*8];
        accn[dt] = __builtin_amdgcn_mfma_f32_16x16x32_bf16(a, bb, accn[dt], 0,0,0);
      }
    }
  }

  float* pp = part + (size_t)(b*NBLK + blk)*PREC0;
  #pragma unroll
  for (int dt=0;dt<4;dt++)
    #pragma unroll
    for (int r=0;r<4;r++)
      pp[(wv*16 + quad*4 + r)*64 + dt*16 + m] = accn[dt][r];
  if (t < 64) pp[4096 + t] = s0acc;
}

// ---------- reduce conv_in partials (f32, 128 rows) -> S0b bf16 + s0 f32 ----------
__global__ __launch_bounds__(256) void k_reduce0(const float* __restrict__ part,
                                                 short* __restrict__ s0b,
                                                 float* __restrict__ s0v){
  int b = blockIdx.y;
  int ce = blockIdx.x*256 + threadIdx.x;
  if (ce >= PREC0) return;
  const float* base = part + (size_t)b*NBLK*PREC0 + ce;
  float acc[8];
  #pragma unroll
  for (int j=0;j<8;j++) acc[j]=0.f;
  #pragma unroll 1
  for (int p=0; p<NBLK; p+=8){
    #pragma unroll
    for (int j=0;j<8;j++) acc[j] += base[(size_t)(p+j)*PREC0];
  }
  float s = ((acc[0]+acc[1])+(acc[2]+acc[3])) + ((acc[4]+acc[5])+(acc[6]+acc[7]));
  if (ce < 4096) s0b[b*4096 + ce] = f2bs(s);
  else           s0v[b*64 + ce - 4096] = s;
}

// ---------- per-layer: k/i/f GEMMs + KF over 4 tiles; partials x128 ----------
__global__ __launch_bounds__(256,3) void k_layer(
    const short* __restrict__ feat0,
    const short* __restrict__ wkeff, const float* __restrict__ bkeff,
    const short* __restrict__ wieff, const float* __restrict__ bieff,
    const short* __restrict__ wfeff, const float* __restrict__ bfeff,
    short* __restrict__ kfpart)
{
  int b = blockIdx.y;
  int t = threadIdx.x;
  int w = t >> 6, lane = t & 63, m = lane & 15, quad = lane >> 4;
  int rowbase = w*16;

  __shared__ short s_fT[64*136];
  __shared__ short s_kg[64*136];

  bf16x8 Ak[2], Ai[2], Af[2];
  loadAfrag(Ak, wkeff + b*4096, 64, m, quad, w);
  loadAfrag(Ai, wieff + b*4096, 64, m, quad, w);
  loadAfrag(Af, wfeff + b*4096, 64, m, quad, w);

  float bkv[4], biv[4], bfv[4], fs[4], kgs[4];
  #pragma unroll
  for (int r=0;r<4;r++){
    int row = rowbase + quad*4 + r;
    bkv[r] = bkeff[b*64 + row];
    biv[r] = bieff[b*64 + row];
    bfv[r] = bfeff[b*64 + row];
    fs[r] = 0.f; kgs[r] = 0.f;
  }
  f32x4 z4 = {0.f,0.f,0.f,0.f};
  f32x4 accn[4];
  #pragma unroll
  for (int dt=0;dt<4;dt++) accn[dt] = z4;

  for (int tile=0; tile<4; tile++){
    if (tile) __syncthreads();  // previous tile's s_fT/s_kg readers done
    const short* fb = feat0 + ((size_t)b*NPIX + blockIdx.x*512 + tile*128)*64;

    // stage s_fT ([c][px]) coalesced
    #pragma unroll
    for (int i=0;i<8;i++){
      int chunk = t + i*256;
      int px = chunk >> 4, c0 = (chunk & 15)*4;
      short4v xv = *(const short4v*)(fb + px*64 + c0);
      #pragma unroll
      for (int j=0;j<4;j++) s_fT[(c0+j)*136 + px] = xv[j];
    }

    // k/i/f GEMMs: B-frags direct from global (independent of s_fT)
    #pragma unroll
    for (int half=0; half<2; half++){
      bf16x8 Bf[2][4];
      #pragma unroll
      for (int kc=0;kc<2;kc++)
        #pragma unroll
        for (int q4=0;q4<4;q4++)
          Bf[kc][q4] = *(const bf16x8*)(fb + ((half*4+q4)*16 + m)*64 + kc*32 + quad*8);
      f32x4 acck[4], acci[4], accf[4];
      #pragma unroll
      for (int q4=0;q4<4;q4++){ acck[q4]=z4; acci[q4]=z4; accf[q4]=z4; }
      #pragma unroll
      for (int kc=0;kc<2;kc++)
        #pragma unroll
        for (int q4=0;q4<4;q4++){
          acck[q4] = __builtin_amdgcn_mfma_f32_16x16x32_bf16(Ak[kc], Bf[kc][q4], acck[q4], 0,0,0);
          acci[q4] = __builtin_amdgcn_mfma_f32_16x16x32_bf16(Ai[kc], Bf[kc][q4], acci[q4], 0,0,0);
          accf[q4] = __builtin_amdgcn_mfma_f32_16x16x32_bf16(Af[kc], Bf[kc][q4], accf[q4], 0,0,0);
        }
      #pragma unroll
      for (int q4=0;q4<4;q4++){
        int nt = half*4 + q4;
        #pragma unroll
        for (int r=0;r<4;r++){
          int row = rowbase + quad*4 + r;
          float kgv = (acck[q4][r] + bkv[r]) * sigmoidf_(acci[q4][r] + biv[r]);
          s_kg[row*136 + nt*16 + m] = f2bs(kgv);
          kgs[r] += kgv;
          fs[r] += sigmoidf_(accf[q4][r] + bfv[r]);
        }
      }
    }
    __syncthreads();   // s_fT visible cross-wave; s_kg own rows

    // KF[c][e] += sum_px kg[c,px]*f0[e,px]
    #pragma unroll
    for (int kc4=0; kc4<4; kc4++){
      bf16x8 a = *(const bf16x8*)&s_kg[(rowbase + m)*136 + kc4*32 + quad*8];
      #pragma unroll
      for (int dt=0; dt<4; dt++){
        bf16x8 bx = *(const bf16x8*)&s_fT[(dt*16 + m)*136 + kc4*32 + quad*8];
        accn[dt] = __builtin_amdgcn_mfma_f32_16x16x32_bf16(a, bx, accn[dt], 0,0,0);
      }
    }
  }

  #pragma unroll
  for (int off=1; off<16; off<<=1)
    #pragma unroll
    for (int r=0;r<4;r++){
      fs[r]  += __shfl_xor(fs[r],  off, 64);
      kgs[r] += __shfl_xor(kgs[r], off, 64);
    }
  short* kp = kfpart + (size_t)(b*NBLK + blockIdx.x)*PREC;
  #pragma unroll
  for (int dt=0;dt<4;dt++)
    #pragma unroll
    for (int r=0;r<4;r++)
      kp[(rowbase + quad*4 + r)*64 + dt*16 + m] = f2bs(accn[dt][r]);
  if (m == 0){
    #pragma unroll
    for (int r=0;r<4;r++){
      int row = rowbase + quad*4 + r;
      kp[4096 + row] = f2bs(fs[r]);
      kp[4160 + row] = f2bs(kgs[r]);
    }
  }
}

// ---------- reduce k_layer partials (bf16, 128 rows) ----------
__global__ __launch_bounds__(256) void k_reduce(const short* __restrict__ kfpart,
                                                short* __restrict__ kfred,
                                                float* __restrict__ fsK,
                                                float* __restrict__ kgsK){
  int b = blockIdx.y;
  int ce = blockIdx.x*256 + threadIdx.x;
  if (ce >= PREC) return;
  const short* base = kfpart + (size_t)b*NBLK*PREC + ce;
  float acc[8];
  #pragma unroll
  for (int j=0;j<8;j++) acc[j]=0.f;
  #pragma unroll 1
  for (int p=0; p<NBLK; p+=8){
    #pragma unroll
    for (int j=0;j<8;j++) acc[j] += bs2f(base[(size_t)(p+j)*PREC]);
  }
  float s = ((acc[0]+acc[1])+(acc[2]+acc[3])) + ((acc[4]+acc[5])+(acc[6]+acc[7]));
  if (ce < 4096)      kfred[b*4096 + ce] = f2bs(s);
  else if (ce < 4160) fsK[b*64 + ce - 4096] = s;
  else                kgsK[b*64 + ce - 4160] = s;
}

// ---------- compose: mem update + affine-state composition + next-layer folding ----------
__global__ __launch_bounds__(256) void k_compose(
    int phase,
    float* __restrict__ E, float* __restrict__ dvec,
    short* __restrict__ cxt, float* __restrict__ dx,
    short* __restrict__ wkeff, short* __restrict__ wieff,
    short* __restrict__ wfeff, short* __restrict__ wvx,
    float* __restrict__ bkeff, float* __restrict__ bieff,
    float* __restrict__ bfeff, float* __restrict__ bvx,
    const short* __restrict__ kfred, const float* __restrict__ fsK,
    const float* __restrict__ kgsK,
    const float* __restrict__ hidden_in, float* __restrict__ hidden_out,
    const short* __restrict__ S0b, const float* __restrict__ s0v,
    const float* __restrict__ gammaP, const float* __restrict__ betaP,
    const short* __restrict__ Wkb, const short* __restrict__ Wvb,
    const short* __restrict__ Wgb, const short* __restrict__ Wpb,
    const short* __restrict__ Wqtb, const float* __restrict__ WqF,
    const float* __restrict__ bqP, const float* __restrict__ bkP,
    const float* __restrict__ bvP, const float* __restrict__ bgP,
    const float* __restrict__ bpP,
    const float* __restrict__ WoutF, float* __restrict__ wtoutE,
    float* __restrict__ btap)
{
  int b = blockIdx.x, t = threadIdx.x;
  int w = t >> 6, lane = t & 63, m = lane & 15, quad = lane >> 4;
  __shared__ short sh1[64*72];
  __shared__ short sh2[64*72];
  __shared__ float sT[64*68];
  __shared__ float sF[64*68];
  __shared__ float sv_fm[64], sv_kgs[64], sv_u[64], sv_g[64];
  __shared__ float sv_A[64], sv_B[64], sv_dx[64], sv_sum[64], sv_sq[64], sv_gr[16];
  f32x4 z4 = {0.f,0.f,0.f,0.f};
  const float invN = 1.0f/65536.0f;

  if (phase == 0){
    #pragma unroll
    for (int i=0;i<16;i++){
      E[b*4096 + t + i*256] = 0.f;
      int idx = t + i*256;
      sF[(idx>>6)*68 + (idx&63)] = 0.f;
    }
    if (t < 64){ dvec[b*64+t] = 0.f; sv_g[t] = 0.f; }
    __syncthreads();
  } else {
    int lay = phase - 1;
    if (t < 64){
      sv_fm[t]  = fsK[b*64+t]*invN;
      sv_kgs[t] = kgsK[b*64+t]*invN;
      float u = bqP[lay*64+t];
      const float* wqrow = WqF + lay*4096 + t*64;
      for (int e=0;e<64;e++) u += wqrow[e]*dx[b*64+e];
      sv_u[t] = u;
    }
    __syncthreads();
    {
      bf16x8 A[2];
      loadAfrag(A, kfred + b*4096, 64, m, quad, w);
      f32x4 o4[4];
      gemm64(A, wvx + b*4096, 64, m, quad, o4);
      #pragma unroll
      for (int dt=0;dt<4;dt++)
        #pragma unroll
        for (int r=0;r<4;r++){
          int c = w*16 + quad*4 + r, d = dt*16 + m;
          float pm = hidden_in[(size_t)(b*NLAYER+lay)*4096 + c*64 + d];
          float nm = sv_fm[c]*pm + o4[dt][r]*invN + sv_kgs[c]*bvx[b*64+d];
          hidden_out[(size_t)(b*NLAYER+lay)*4096 + c*64 + d] = nm;
          sh1[c*72 + d] = f2bs(nm);
        }
    }
    __syncthreads();
    {
      bf16x8 A[2];
      loadAfrag(A, Wpb + lay*4096, 64, m, quad, w);
      f32x4 o4[4];
      gemm64(A, sh1, 72, m, quad, o4);
      #pragma unroll
      for (int ct=0;ct<4;ct++)
        #pragma unroll
        for (int r=0;r<4;r++)
          sh2[(w*16 + quad*4 + r)*72 + ct*16 + m] = f2bs(o4[ct][r]);
    }
    __syncthreads();
    if (t < 64){
      float acc = 0.f;
      for (int c=0;c<64;c++) acc += bs2f(sh2[t*72+c])*sv_u[c];
      sv_g[t] = bpP[lay*64+t] + 0.125f*acc;
    }
    {
      bf16x8 A[2];
      loadAfrag(A, sh2, 72, m, quad, w);
      f32x4 o4[4];
      gemm64(A, Wqtb + lay*4096, 64, m, quad, o4);
      #pragma unroll
      for (int et=0;et<4;et++)
        #pragma unroll
        for (int r=0;r<4;r++)
          sh1[(w*16 + quad*4 + r)*72 + et*16 + m] = f2bs(o4[et][r]);
    }
    __syncthreads();
    {
      bf16x8 A[2];
      loadAfrag(A, sh1, 72, m, quad, w);
      f32x4 o4[4];
      gemm64(A, cxt + b*4096, 64, m, quad, o4);
      #pragma unroll
      for (int et=0;et<4;et++)
        #pragma unroll
        for (int r=0;r<4;r++)
          sF[(w*16 + quad*4 + r)*68 + et*16 + m] = 0.125f*o4[et][r];
    }
    __syncthreads();
  }

  if (phase < NLAYER){
    int j = phase;
    #pragma unroll
    for (int i=0;i<16;i++){
      int idx = t + i*256;
      int c = idx >> 6, e = idx & 63;
      float v = E[b*4096 + idx] + sF[c*68 + e] + (c==e ? 1.f : 0.f);
      sh2[c*72 + e] = f2bs(v);
    }
    __syncthreads();
    {
      bf16x8 A[2];
      loadAfrag(A, sh2, 72, m, quad, w);
      f32x4 o4[4];
      gemm64(A, S0b + b*4096, 64, m, quad, o4);
      #pragma unroll
      for (int et=0;et<4;et++)
        #pragma unroll
        for (int r=0;r<4;r++)
          sT[(w*16 + quad*4 + r)*68 + et*16 + m] = o4[et][r];
    }
    __syncthreads();
    if (t < 64){
      int c = t;
      float q = 0.f, m1 = 0.f;
      const float* Erow = E + b*4096 + c*64;
      for (int e=0;e<64;e++){
        float Ce = Erow[e] + sF[c*68+e] + (e==c ? 1.f : 0.f);
        q  += sT[c*68+e]*Ce;
        m1 += Ce*s0v[b*64+e];
      }
      float dc = dvec[b*64+c] + sv_g[c];
      sv_sum[c] = m1 + 65536.f*dc;
      sv_sq[c]  = q + 2.f*dc*m1 + 65536.f*dc*dc;
    }
    __syncthreads();
    if (t < 8){
      float s=0.f, sq=0.f;
      for (int c=t*8; c<t*8+8; c++){ s += sv_sum[c]; sq += sv_sq[c]; }
      float mu = s*(1.f/(8.f*65536.f));
      float var = sq*(1.f/(8.f*65536.f)) - mu*mu;
      sv_gr[t*2] = mu;
      sv_gr[t*2+1] = rsqrtf(var + 1e-5f);
    }
    __syncthreads();
    if (t < 64){
      int g = t >> 3;
      float A = sv_gr[g*2+1]*gammaP[j*64+t];
      sv_A[t] = A;
      sv_B[t] = betaP[j*64+t] - sv_gr[g*2]*A;
      float dxv = A*(dvec[b*64+t] + sv_g[t]) + sv_B[t];
      sv_dx[t] = dxv;
      dx[b*64+t] = dxv;
    }
    __syncthreads();
    #pragma unroll
    for (int i=0;i<16;i++){
      int idx = t + i*256;
      int c = idx >> 6, e = idx & 63;
      float v = (E[b*4096 + idx] + sF[c*68+e] + (c==e ? 1.f : 0.f))*sv_A[c];
      cxt[b*4096 + e*64 + c] = f2bs(v);
    }
    __syncthreads();
    {
      bf16x8 A[2]; f32x4 o4[4];
      loadAfrag(A, Wkb + j*4096, 64, m, quad, w);
      gemm64(A, cxt + b*4096, 64, m, quad, o4);
      #pragma unroll
      for (int et=0;et<4;et++)
        #pragma unroll
        for (int r=0;r<4;r++)
          wkeff[b*4096 + (w*16+quad*4+r)*64 + et*16+m] = f2bs(o4[et][r]);
      loadAfrag(A, Wgb + j*8192 + 64*64, 64, m, quad, w);
      gemm64(A, cxt + b*4096, 64, m, quad, o4);
      #pragma unroll
      for (int et=0;et<4;et++)
        #pragma unroll
        for (int r=0;r<4;r++)
          wieff[b*4096 + (w*16+quad*4+r)*64 + et*16+m] = f2bs(o4[et][r]);
      loadAfrag(A, Wgb + j*8192, 64, m, quad, w);
      gemm64(A, cxt + b*4096, 64, m, quad, o4);
      #pragma unroll
      for (int et=0;et<4;et++)
        #pragma unroll
        for (int r=0;r<4;r++)
          wfeff[b*4096 + (w*16+quad*4+r)*64 + et*16+m] = f2bs(o4[et][r]);
      loadAfrag(A, Wvb + j*4096, 64, m, quad, w);
      gemm64(A, cxt + b*4096, 64, m, quad, o4);
      #pragma unroll
      for (int et=0;et<4;et++)
        #pragma unroll
        for (int r=0;r<4;r++)
          wvx[b*4096 + (w*16+quad*4+r)*64 + et*16+m] = f2bs(o4[et][r]);
    }
    if (t < 64){
      float aK = bkP[j*64+t], aI = bgP[j*128+64+t], aF = bgP[j*128+t], aV = bvP[j*64+t];
      const short* wk = Wkb + j*4096 + t*64;
      const short* wi = Wgb + j*8192 + (64+t)*64;
      const short* wf = Wgb + j*8192 + t*64;
      const short* wvr = Wvb + j*4096 + t*64;
      for (int e=0;e<64;e++){
        float d_ = sv_dx[e];
        aK += bs2f(wk[e])*d_;
        aI += bs2f(wi[e])*d_;
        aF += bs2f(wf[e])*d_;
        aV += bs2f(wvr[e])*d_;
      }
      bkeff[b*64+t] = aK; bieff[b*64+t] = aI;
      bfeff[b*64+t] = aF; bvx[b*64+t] = aV;
    }
    // persist AFTER all readers (phase NLAYER must NOT write — R9's race)
    #pragma unroll
    for (int i=0;i<16;i++){
      int idx = t + i*256;
      E[b*4096 + idx] += sF[(idx>>6)*68 + (idx&63)];
    }
    if (t < 64) dvec[b*64+t] += sv_g[t];
  } else {
    #pragma unroll 1
    for (int i=0;i<5;i++){
      int idxq = t + i*256;
      if (idxq < 1152){
        int o = idxq / 576, rem = idxq % 576;
        int k = rem >> 6, e = rem & 63;
        float acc = 0.f;
        for (int d=0; d<64; d++){
          float Cde = E[b*4096 + d*64 + e] + sF[d*68+e] + (d==e ? 1.f : 0.f);
          acc += WoutF[o*576 + d*9 + k]*Cde;
        }
        wtoutE[b*1152 + (o*9+k)*64 + e] = acc;
      }
    }
    if (t < 18){
      int o = t/9, k = t%9;
      float acc = 0.f;
      for (int d=0; d<64; d++)
        acc += WoutF[o*576 + d*9 + k]*(dvec[b*64+d] + sv_g[d]);
      btap[b*18 + t] = acc;
    }
  }
}

// ---------- conv3x3 64->2 on folded weights + residual ----------
__global__ __launch_bounds__(256) void k_conv_out(
    const short* __restrict__ feat0, const float* __restrict__ wtoutE,
    const float* __restrict__ btap, const float* __restrict__ bias,
    const float* __restrict__ xin, float* __restrict__ out){
  int b = blockIdx.y;
  int y = blockIdx.x;
  int xx = threadIdx.x;
  float acc0 = bias[0], acc1 = bias[1];
  #pragma unroll
  for (int dy=-1; dy<=1; dy++){
    int yy = y + dy;
    if (yy < 0 || yy >= HDIM) continue;
    #pragma unroll
    for (int dx=-1; dx<=1; dx++){
      int xc = xx + dx;
      if (xc >= 0 && xc < HDIM){
        int k = (dy+1)*3 + dx+1;
        const short* fp = feat0 + ((size_t)b*NPIX + yy*HDIM + xc)*64;
        const float* w0 = wtoutE + b*1152 + k*64;
        const float* w1 = wtoutE + b*1152 + 576 + k*64;
        acc0 += btap[b*18 + k];
        acc1 += btap[b*18 + 9 + k];
        #pragma unroll
        for (int c4=0;c4<16;c4++){
          short4v xs = *(const short4v*)(fp + c4*4);
          f32x4 wv0 = *(const f32x4*)(w0 + c4*4);
          f32x4 wv1 = *(const f32x4*)(w1 + c4*4);
          #pragma unroll
          for (int j=0;j<4;j++){
            float f = bs2f(xs[j]);
            acc0 += f*wv0[j];
            acc1 += f*wv1[j];
          }
        }
      }
    }
  }
  size_t p0 = (size_t)(b*2+0)*NPIX + y*HDIM + xx;
  size_t p1 = (size_t)(b*2+1)*NPIX + y*HDIM + xx;
  out[p0] = acc0 + xin[p0];
  out[p1] = acc1 + xin[p1];
}

extern "C" void kernel_launch(void* const* d_in, const int* in_sizes, int n_in,
                              void* d_out, int out_size, void* d_ws, size_t ws_size,
                              hipStream_t stream){
  char* ws = (char*)d_ws;
  short* feat0 = (short*)(ws + OFS_FEAT0);
  float* part  = (float*)(ws + OFS_PART);
  short* kfp   = (short*)(ws + OFS_PART);      // aliased (disjoint lifetime)
  short* kfred = (short*)(ws + OFS_KFRED);
  short* s0b   = (short*)(ws + OFS_S0B);
  float* s0v   = (float*)(ws + OFS_S0V);
  float* fsK   = (float*)(ws + OFS_FS);
  float* kgsK  = (float*)(ws + OFS_KGS);
  float* E     = (float*)(ws + OFS_E);
  float* dvec  = (float*)(ws + OFS_DVEC);
  short* cxt   = (short*)(ws + OFS_CXT);
  float* dx    = (float*)(ws + OFS_DX);
  short* wkeff = (short*)(ws + OFS_WKEFF);
  short* wieff = (short*)(ws + OFS_WIEFF);
  short* wfeff = (short*)(ws + OFS_WFEFF);
  short* wvx   = (short*)(ws + OFS_WVX);
  float* bkeff = (float*)(ws + OFS_BKEFF);
  float* bieff = (float*)(ws + OFS_BIEFF);
  float* bfeff = (float*)(ws + OFS_BFEFF);
  float* bvx   = (float*)(ws + OFS_BVX);
  short* wkb   = (short*)(ws + OFS_WKB);
  short* wvb   = (short*)(ws + OFS_WVB);
  short* wgb   = (short*)(ws + OFS_WGB);
  short* wpb   = (short*)(ws + OFS_WPB);
  short* wqtb  = (short*)(ws + OFS_WQTB);
  float* wtoutE= (float*)(ws + OFS_WTOUTE);
  float* btap  = (float*)(ws + OFS_BTAP);

  const float* x      = (const float*)d_in[0];
  const float* hidden = (const float*)d_in[1];
  const float* W_in   = (const float*)d_in[2];
  const float* b_in   = (const float*)d_in[3];
  const float* gamma  = (const float*)d_in[4];
  const float* beta   = (const float*)d_in[5];
  const float* Wq     = (const float*)d_in[6];
  const float* bq     = (const float*)d_in[7];
  const float* Wk     = (const float*)d_in[8];
  const float* bk     = (const float*)d_in[9];
  const float* Wv     = (const float*)d_in[10];
  const float* bv     = (const float*)d_in[11];
  const float* Wg     = (const float*)d_in[12];
  const float* bg     = (const float*)d_in[13];
  const float* Wp     = (const float*)d_in[14];
  const float* bp     = (const float*)d_in[15];
  const float* W_out  = (const float*)d_in[16];
  const float* b_out  = (const float*)d_in[17];

  float* out        = (float*)d_out;
  float* hidden_out = out + BATCH*2*NPIX;

  k_prepw<<<dim3(128), dim3(256), 0, stream>>>(Wk, Wv, Wg, Wp, Wq,
                                               wkb, wvb, wgb, wpb, wqtb);
  k_conv_in<<<dim3(NBLK, BATCH), dim3(256), 0, stream>>>(x, W_in, b_in, feat0, part);
  k_reduce0<<<dim3((PREC0+255)/256, BATCH), dim3(256), 0, stream>>>(part, s0b, s0v);

  #define COMPOSE_ARGS E, dvec, cxt, dx, wkeff, wieff, wfeff, wvx, \
      bkeff, bieff, bfeff, bvx, kfred, fsK, kgsK, hidden, hidden_out, \
      s0b, s0v, gamma, beta, wkb, wvb, wgb, wpb, wqtb, Wq, \
      bq, bk, bv, bg, bp, W_out, wtoutE, btap

  k_compose<<<dim3(BATCH), dim3(256), 0, stream>>>(0, COMPOSE_ARGS);
  for (int l=0; l<NLAYER; l++){
    k_layer<<<dim3(NBLK, BATCH), dim3(256), 0, stream>>>(
        feat0, wkeff, bkeff, wieff, bieff, wfeff, bfeff, kfp);
    k_reduce<<<dim3((PREC+255)/256, BATCH), dim3(256), 0, stream>>>(kfp, kfred, fsK, kgsK);
    k_compose<<<dim3(BATCH), dim3(256), 0, stream>>>(l+1, COMPOSE_ARGS);
  }
  k_conv_out<<<dim3(HDIM, BATCH), dim3(256), 0, stream>>>(feat0, wtoutE, btap, b_out, x, out);
}